// Round 1
// baseline (429.861 us; speedup 1.0000x reference)
//
#include <hip/hip_runtime.h>
#include <hip/hip_bf16.h>
#include <stdint.h>

// Mahalanobis loss: out = mean_n (f_n - mu)^T C (f_n - mu),  N=131072, D=512.
// Strategy: bf16 MFMA GEMM T0 = F @ Cb (raw F, no mean-sub), fused epilogue
//   quad[n] = sum_e (T0[n,e] - w[e]) * (f[n,e] - mu[e]),  w = Cb^T mu  (exact algebra)
// Memory-bound problem: unique traffic = 268 MB feature + 1 MB C -> ~43 us floor.
// A-tile K-order is permuted so the last 4 K-chunks == this block's e-columns and
// remain in the 4-slot LDS buffer for the epilogue (no feature re-read).

typedef __attribute__((ext_vector_type(8))) short short8;
typedef __attribute__((ext_vector_type(4))) float floatx4;

static constexpr int NROWS = 131072;
static constexpr int DDIM  = 512;
static constexpr int BM = 128, BN = 128, BK = 32;
static constexpr int FS_STRIDE = 136;  // shorts: 128 cols + 8 pad (272 B, 16B-aligned rows)
static constexpr int BS_STRIDE = 40;   // shorts: 32 cols + 8 pad (80 B, 16B-aligned rows)

__device__ __forceinline__ short f2bf(float f) {
  __bf16 b = (__bf16)f;                 // RNE f32->bf16
  return __builtin_bit_cast(short, b);
}
__device__ __forceinline__ float bf2f(short s) {
  __bf16 b = __builtin_bit_cast(__bf16, s);
  return (float)b;
}

// ---------------- prep: Ct[e][k] = bf16(C[k][e]);  w[e] = sum_k mu[k]*bf16(C[k][e]); zero out ----
__global__ __launch_bounds__(256) void maha_prep(const float* __restrict__ C,
                                                 const float* __restrict__ mean,
                                                 short* __restrict__ Ct,
                                                 float* __restrict__ w,
                                                 float* __restrict__ out) {
  const int e = blockIdx.x;     // 512 blocks, one output column of Ct each
  const int t = threadIdx.x;    // 256 threads cover k = t and t+256
  float c0 = C[t * DDIM + e];
  float c1 = C[(t + 256) * DDIM + e];
  short b0 = f2bf(c0), b1 = f2bf(c1);
  Ct[e * DDIM + t]       = b0;
  Ct[e * DDIM + t + 256] = b1;
  // w must use the *bf16-rounded* C so the mean-folding algebra is exact.
  float p = mean[t] * bf2f(b0) + mean[t + 256] * bf2f(b1);
  __shared__ float red[256];
  red[t] = p;
  __syncthreads();
  for (int off = 128; off > 0; off >>= 1) {
    if (t < off) red[t] += red[t + off];
    __syncthreads();
  }
  if (t == 0) {
    w[e] = red[0];
    if (e == 0) out[0] = 0.0f;   // d_out is poisoned 0xAA before every launch
  }
}

// ---------------- main fused GEMM + quadratic-form reduction ----------------
__global__ __launch_bounds__(256, 3) void maha_main(const float* __restrict__ F,
                                                    const float* __restrict__ mean,
                                                    const short* __restrict__ Ct,
                                                    const float* __restrict__ w,
                                                    float* __restrict__ out) {
  __shared__ short Fs[BM * FS_STRIDE];  // 4 K-slots of the A tile (bf16 raw feature)
  __shared__ short Bs[BN * BS_STRIDE];  // current B tile: Ct rows (e-major, k-contig)
  __shared__ float red[4];

  // XCD swizzle: 4 blocks sharing an mtile get identical bid%8 (same XCD), 8 apart.
  const int b = blockIdx.x;
  const int mtile = ((b >> 5) << 3) | (b & 7);   // 0..1023
  const int etile = (b >> 3) & 3;                // 0..3
  const int m0 = mtile * BM;
  const int e0 = etile * BN;

  const int t    = threadIdx.x;
  const int lane = t & 63;
  const int wave = t >> 6;
  const int wm = wave >> 1, wn = wave & 1;       // 2x2 wave grid of 64x64
  const int l15  = lane & 15;
  const int quad = lane >> 4;

  // staging mapping: 2 threads per 128-row, 16 elems (64B) each
  const int rA = t >> 1;
  const int hA = t & 1;
  const float* Fbase = F  + (size_t)(m0 + rA) * DDIM + hA * 16;
  const short* Cbase = Ct + (size_t)(e0 + rA) * DDIM + hA * 16;

  floatx4 pa[4];
  short8  pb0, pb1;
  const int chunk_base = (e0 >> 5) + 4;          // K-chunk permutation start

  auto loadpf = [&](int c) {
    const int ch = (chunk_base + c) & 15;        // last 4 iters == own e-range, ascending
    const floatx4* fp = (const floatx4*)(Fbase + ch * 32);
    pa[0] = fp[0]; pa[1] = fp[1]; pa[2] = fp[2]; pa[3] = fp[3];
    const short8* bp = (const short8*)(Cbase + ch * 32);
    pb0 = bp[0]; pb1 = bp[1];
  };

  floatx4 acc[4][4];
#pragma unroll
  for (int i = 0; i < 4; i++)
#pragma unroll
    for (int j = 0; j < 4; j++) acc[i][j] = floatx4{0.f, 0.f, 0.f, 0.f};

  loadpf(0);

#pragma unroll 4
  for (int c = 0; c < 16; ++c) {
    const int s = c & 3;
    __syncthreads();                             // prior iter's LDS readers done
    // convert prefetched fp32 feature -> bf16, store into slot s
    short8 w0, w1;
#pragma unroll
    for (int q = 0; q < 2; q++)
#pragma unroll
      for (int k = 0; k < 4; k++) {
        w0[q * 4 + k] = f2bf(pa[q][k]);
        w1[q * 4 + k] = f2bf(pa[q + 2][k]);
      }
    *(short8*)&Fs[rA * FS_STRIDE + s * 32 + hA * 16]     = w0;
    *(short8*)&Fs[rA * FS_STRIDE + s * 32 + hA * 16 + 8] = w1;
    *(short8*)&Bs[rA * BS_STRIDE + hA * 16]              = pb0;
    *(short8*)&Bs[rA * BS_STRIDE + hA * 16 + 8]          = pb1;
    if (c < 15) loadpf(c + 1);                   // prefetch overlaps this iter's MFMA
    __syncthreads();                             // tiles ready

    short8 af[4], bfv[4];
#pragma unroll
    for (int i = 0; i < 4; i++)
      af[i] = *(const short8*)&Fs[(wm * 64 + i * 16 + l15) * FS_STRIDE + s * 32 + quad * 8];
#pragma unroll
    for (int j = 0; j < 4; j++)
      bfv[j] = *(const short8*)&Bs[(wn * 64 + j * 16 + l15) * BS_STRIDE + quad * 8];
#pragma unroll
    for (int i = 0; i < 4; i++)
#pragma unroll
      for (int j = 0; j < 4; j++)
        acc[i][j] = __builtin_amdgcn_mfma_f32_16x16x32_bf16(af[i], bfv[j], acc[i][j], 0, 0, 0);
  }

  // Epilogue: quad partial = sum (acc - w[e]) * (f - mu[e]); f (bf16) is in Fs slots 0..3,
  // which now hold exactly K-chunks etile*4 .. etile*4+3 == columns [e0, e0+128).
  float psum = 0.f;
#pragma unroll
  for (int j = 0; j < 4; j++) {
    const int e_loc = wn * 64 + j * 16 + l15;
    const float wj = w[e0 + e_loc];
    const float mj = mean[e0 + e_loc];
#pragma unroll
    for (int i = 0; i < 4; i++) {
      const int m_base = wm * 64 + i * 16 + quad * 4;
#pragma unroll
      for (int r = 0; r < 4; r++) {
        const float fv = bf2f(Fs[(m_base + r) * FS_STRIDE + e_loc]);
        psum += (acc[i][j][r] - wj) * (fv - mj);
      }
    }
  }

  // reduce 64 lanes -> 4 waves -> block -> global atomic
#pragma unroll
  for (int off = 32; off > 0; off >>= 1) psum += __shfl_down(psum, off);
  if (lane == 0) red[wave] = psum;
  __syncthreads();
  if (t == 0) {
    const float tot = (red[0] + red[1] + red[2] + red[3]) * (1.0f / (float)NROWS);
    atomicAdd(out, tot);
  }
}

extern "C" void kernel_launch(void* const* d_in, const int* in_sizes, int n_in,
                              void* d_out, int out_size, void* d_ws, size_t ws_size,
                              hipStream_t stream) {
  const float* feature = (const float*)d_in[0];   // [131072, 512] fp32
  const float* mean    = (const float*)d_in[1];   // [512] fp32
  const float* invcov  = (const float*)d_in[2];   // [512, 512] fp32
  float* out = (float*)d_out;                     // scalar fp32

  // workspace layout: w[512] fp32 at +0, Ct[512*512] bf16 at +4096  (needs ~516 KB)
  float* w  = (float*)d_ws;
  short* Ct = (short*)((char*)d_ws + 4096);

  maha_prep<<<512, 256, 0, stream>>>(invcov, mean, Ct, w, out);
  maha_main<<<4096, 256, 0, stream>>>(feature, mean, Ct, w, out);
}